// Round 24
// baseline (175.173 us; speedup 1.0000x reference)
//
#include <hip/hip_runtime.h>

#define N_NODES 100000
#define N_EDGES 1600000
#define IN_DIM 256
#define OUT_DIM 128
#define BROWS 100    // rows per bucket
#define NBK 1000     // buckets (100000/100)
#define PBLK 128     // partition blocks
#define EPB 12500    // edges per partition block

typedef __attribute__((ext_vector_type(4))) float f32x4;
typedef __attribute__((ext_vector_type(8))) short s16x8;

__device__ inline unsigned short f2bf(float f) {
    union { float f; unsigned int u; } a; a.f = f;
    unsigned int r = a.u + 0x7fffu + ((a.u >> 16) & 1u);
    return (unsigned short)(r >> 16);
}
__device__ inline float bf2f(unsigned short h) {
    union { unsigned int u; float f; } a; a.u = ((unsigned int)h) << 16;
    return a.f;
}
__device__ inline void gload16(const void* g, void* l) {
    __builtin_amdgcn_global_load_lds(
        (const __attribute__((address_space(1))) void*)g,
        (__attribute__((address_space(3))) void*)l, 16, 0, 0);
}

// ---- Kernel 0 (fused): wt transpose + per-(block,bucket) histogram + u/v ----
__global__ __launch_bounds__(256) void kprep(
        const float* __restrict__ fsW, const float* __restrict__ fw,
        const float* __restrict__ W, const int* __restrict__ row,
        float* __restrict__ u, float* __restrict__ v,
        unsigned short* __restrict__ wt, int* __restrict__ hist_t) {
    __shared__ int h[NBK];
    __shared__ float wi[128], wj[128];
    const int t = threadIdx.x, blk = blockIdx.x;
    if (blk < PBLK) {
        wt[blk * 256 + t] = f2bf(W[(size_t)t * 128 + blk]);
        for (int b = t; b < NBK; b += 256) h[b] = 0;
        __syncthreads();
        const int e0 = blk * EPB;
        for (int i = t; i < EPB; i += 256)
            atomicAdd(&h[row[e0 + i] / BROWS], 1);
        __syncthreads();
        for (int b = t; b < NBK; b += 256)
            hist_t[b * PBLK + blk] = h[b];
    } else {
        if (t < 128) wi[t] = fw[t]; else wj[t - 128] = fw[t];
        __syncthreads();
        const float* rowp = fsW + (size_t)t * OUT_DIM;
        float su = 0.f, sv = 0.f;
        for (int d = 0; d < 128; d += 4) {
            float4 a = *(const float4*)(rowp + d);
            su += a.x * wi[d] + a.y * wi[d + 1] + a.z * wi[d + 2] + a.w * wi[d + 3];
            sv += a.x * wj[d] + a.y * wj[d + 1] + a.z * wj[d + 2] + a.w * wj[d + 3];
        }
        u[t] = su; v[t] = sv;
    }
}

// ------- Kernel 3: bucket sums (int4) + exclusive scan (single block) -------
__global__ __launch_bounds__(1024) void kbscan(const int* __restrict__ hist_t,
                                               int* __restrict__ bpre) {
    __shared__ int s[1024];
    const int t = threadIdx.x;
    int v = 0;
    if (t < NBK) {
        const int4* hp = (const int4*)(hist_t + t * PBLK);
#pragma unroll 4
        for (int k = 0; k < PBLK / 4; ++k) {
            int4 a = hp[k];
            v += a.x + a.y + a.z + a.w;
        }
    }
    s[t] = v;
    __syncthreads();
    for (int off = 1; off < 1024; off <<= 1) {
        int nv = (t >= off) ? s[t - off] : 0;
        __syncthreads();
        s[t] += nv;
        __syncthreads();
    }
    if (t < NBK) bpre[t] = s[t] - v;
    if (t == 1023) bpre[NBK] = s[1023];
}

// ------- Kernel 4: per-(bucket,block) offsets -------
__global__ __launch_bounds__(128) void koff(const int* __restrict__ hist_t,
                                            const int* __restrict__ bpre,
                                            int* __restrict__ off) {
    const int b = blockIdx.x, t = threadIdx.x;
    const int lane = t & 63, w = t >> 6;
    int v = hist_t[b * PBLK + t];
    int s = v;
#pragma unroll
    for (int o = 1; o < 64; o <<= 1) { int tt = __shfl_up(s, o); if (lane >= o) s += tt; }
    __shared__ int ws2[2];
    if (lane == 63) ws2[w] = s;
    __syncthreads();
    int base = (w == 1) ? ws2[0] : 0;
    off[b * PBLK + t] = bpre[b] + base + (s - v);
}

// ------- Kernel G (fused): blocks [0,PBLK) = edge partition; rest = MFMA GEMM -------
// gemm: DOUBLE-BUFFERED async f32 staging (global_load_lds, counted vmcnt(4),
// raw s_barrier), f32->bf16 via v_cvt_pk in MFMA phase, si/sj from LDS.
__global__ __launch_bounds__(256) void gpart(
        const float* __restrict__ x, const unsigned short* __restrict__ wt,
        const float* __restrict__ u, const float* __restrict__ v,
        unsigned short* __restrict__ psb, float* __restrict__ si, float* __restrict__ sj,
        const int* __restrict__ row, const int* __restrict__ col,
        const int* __restrict__ off, unsigned int* __restrict__ part) {
    __shared__ char ldsraw[32896];   // 2 x 16 KB stage bufs; C-tile/cursors reuse buf0

    const int t = threadIdx.x;

    if (blockIdx.x < PBLK) {
        // ================= kpart1: partition edges into bucket runs =================
        int* cur = (int*)ldsraw;
        const int blk = blockIdx.x;
        for (int b = t; b < NBK; b += 256) cur[b] = off[b * PBLK + blk];
        __syncthreads();
        const int e0 = blk * EPB;
        for (int i = t; i < EPB; i += 256) {
            int r = row[e0 + i], c = col[e0 + i];
            int b = r / BROWS;
            int rl = r - b * BROWS;
            int pos = atomicAdd(&cur[b], 1);
            part[pos] = ((unsigned)rl << 17) | (unsigned)c;
        }
        return;
    }

    // ================= gemm =================
    const int wave = t >> 6, lane = t & 63;
    const int l15 = lane & 15, lhi = lane >> 4;
    const int rw = t >> 2, quad = t & 3;
    const int brow = (blockIdx.x - PBLK) * 64;
    const int gnode = brow + rw;
    const bool valid = gnode < N_NODES;

    f32x4 acc[4][2];
#pragma unroll
    for (int mi = 0; mi < 4; ++mi)
#pragma unroll
        for (int ni = 0; ni < 2; ++ni) acc[mi][ni] = (f32x4){0.f, 0.f, 0.f, 0.f};
    float su = 0.f, sv = 0.f;

    // stage issue: 4 x gload16 per thread; src pre-swizzled (involution), LDS linear
#define STAGE(PH, BUFOFS)                                                        \
    {                                                                            \
        _Pragma("unroll")                                                        \
        for (int i_ = 0; i_ < 4; ++i_) {                                         \
            int lo_ = i_ * 4096 + t * 16;                                        \
            int q_ = lo_ ^ (((lo_ >> 8) & 7) << 4);                              \
            int grow_ = brow + (q_ >> 8);                                        \
            if (grow_ >= N_NODES) grow_ = N_NODES - 1;                           \
            gload16((const char*)x + (size_t)grow_ * 1024 + (PH) * 256 + (q_ & 255), \
                    ldsraw + (BUFOFS) + lo_);                                    \
        }                                                                        \
    }

    STAGE(0, 0);   // prologue

#pragma unroll
    for (int ph = 0; ph < 4; ++ph) {
        const int bufofs = (ph & 1) * 16448;
        // ---- issue next phase's staging into the other buffer ----
        if (ph < 3) {
            STAGE(ph + 1, ((ph + 1) & 1) * 16448);
            asm volatile("s_waitcnt vmcnt(4)" ::: "memory");   // current tile done; next in flight
        } else {
            asm volatile("s_waitcnt vmcnt(0)" ::: "memory");
        }
        __builtin_amdgcn_s_barrier();            // all waves' current-tile loads landed
        __builtin_amdgcn_sched_barrier(0);       // rule #18: pin ds_reads behind the wait

        // ---- MFMA: 2 k-steps; A-frags read f32 from LDS, cvt_pk to bf16 ----
        {
            const unsigned short* wb0 = wt + (size_t)(wave * 32 + l15) * IN_DIM + ph * 64 + lhi * 8;
            s16x8 bfr[2][2];
#pragma unroll
            for (int ks = 0; ks < 2; ++ks) {
                bfr[ks][0] = *(const s16x8*)(wb0 + ks * 32);
                bfr[ks][1] = *(const s16x8*)(wb0 + (size_t)16 * IN_DIM + ks * 32);
            }
#pragma unroll
            for (int ks = 0; ks < 2; ++ks) {
                s16x8 afr[4];
#pragma unroll
                for (int mi = 0; mi < 4; ++mi) {
                    const int r = mi * 16 + l15;
                    const int sw = (r & 7) << 4;
                    const int b0 = r * 256 + ks * 128 + lhi * 32;
                    float4 f0 = *(const float4*)(ldsraw + bufofs + (b0 ^ sw));
                    float4 f1 = *(const float4*)(ldsraw + bufofs + ((b0 + 16) ^ sw));
                    union { unsigned int w[4]; s16x8 s; } cv;
                    asm("v_cvt_pk_bf16_f32 %0, %1, %2" : "=v"(cv.w[0]) : "v"(f0.x), "v"(f0.y));
                    asm("v_cvt_pk_bf16_f32 %0, %1, %2" : "=v"(cv.w[1]) : "v"(f0.z), "v"(f0.w));
                    asm("v_cvt_pk_bf16_f32 %0, %1, %2" : "=v"(cv.w[2]) : "v"(f1.x), "v"(f1.y));
                    asm("v_cvt_pk_bf16_f32 %0, %1, %2" : "=v"(cv.w[3]) : "v"(f1.z), "v"(f1.w));
                    afr[mi] = cv.s;
                }
#pragma unroll
                for (int mi = 0; mi < 4; ++mi)
#pragma unroll
                    for (int ni = 0; ni < 2; ++ni)
                        acc[mi][ni] = __builtin_amdgcn_mfma_f32_16x16x32_bf16(
                            afr[mi], bfr[ks][ni], acc[mi][ni], 0, 0, 0);
            }
        }

        // ---- si/sj partials from the staged f32 tile ----
        {
            const float* up = u + ph * 64 + quad * 16;
            const float* vp = v + ph * 64 + quad * 16;
            const int rb_ = rw * 256 + quad * 64;
            const int sw = (rw & 7) << 4;
#pragma unroll
            for (int c = 0; c < 4; ++c) {
                float4 a = *(const float4*)(ldsraw + bufofs + ((rb_ + c * 16) ^ sw));
                float4 uu = ((const float4*)up)[c];
                float4 vv = ((const float4*)vp)[c];
                su = fmaf(a.x, uu.x, su); su = fmaf(a.y, uu.y, su);
                su = fmaf(a.z, uu.z, su); su = fmaf(a.w, uu.w, su);
                sv = fmaf(a.x, vv.x, sv); sv = fmaf(a.y, vv.y, sv);
                sv = fmaf(a.z, vv.z, sv); sv = fmaf(a.w, vv.w, sv);
            }
        }
        asm volatile("s_waitcnt lgkmcnt(0)" ::: "memory");
        __builtin_amdgcn_s_barrier();   // buf reads done; safe to restage it next iter
    }
#undef STAGE

    su += __shfl_xor(su, 1); su += __shfl_xor(su, 2);
    sv += __shfl_xor(sv, 1); sv += __shfl_xor(sv, 2);
    if (quad == 0 && valid) { si[gnode] = su; sj[gnode] = sv; }

    // ---- C-write: fragments -> LDS ([64][128] bf16, buf0) -> coalesced global ----
    unsigned short* cl = (unsigned short*)ldsraw;
#pragma unroll
    for (int mi = 0; mi < 4; ++mi)
#pragma unroll
        for (int ni = 0; ni < 2; ++ni) {
            const int colb = wave * 32 + ni * 16 + l15;
#pragma unroll
            for (int j = 0; j < 4; ++j)
                cl[(mi * 16 + lhi * 4 + j) * 128 + colb] = f2bf(acc[mi][ni][j]);
        }
    __syncthreads();
    {
        const int rl = t >> 2;
        const int cb = (t & 3) * 32;
        if (brow + rl < N_NODES) {
            const uint4* src = (const uint4*)&cl[rl * 128 + cb];
            uint4* dst = (uint4*)&psb[(size_t)(brow + rl) * OUT_DIM + cb];
            dst[0] = src[0]; dst[1] = src[1]; dst[2] = src[2]; dst[3] = src[3];
        }
    }
}

// ------- Kernel 6: per-bucket row-histogram + local scan -> offs/deg, CSR + value -------
__global__ __launch_bounds__(256) void kpart2(const unsigned int* __restrict__ part,
                                              const int* __restrict__ bpre,
                                              const float* __restrict__ si,
                                              const float* __restrict__ sj,
                                              const float* __restrict__ dia,
                                              const float* __restrict__ fb,
                                              int2* __restrict__ epack,
                                              int* __restrict__ offs,
                                              int* __restrict__ deg) {
    __shared__ int cnt[BROWS];
    __shared__ int cur[BROWS];
    __shared__ float sil[BROWS], dial[BROWS];
    __shared__ int wtot[4];
    const int b = blockIdx.x, t = threadIdx.x;
    const int rbase = b * BROWS;
    if (t < BROWS) {
        cnt[t] = 0;
        sil[t] = si[rbase + t];
        dial[t] = dia[rbase + t];
    }
    __syncthreads();
    const int bstart = bpre[b], bend = bpre[b + 1];
    for (int e = bstart + t; e < bend; e += 256)
        atomicAdd(&cnt[part[e] >> 17], 1);
    __syncthreads();
    {
        int vv = (t < BROWS) ? cnt[t] : 0;
        int lane = t & 63, w = t >> 6;
        int s = vv;
#pragma unroll
        for (int o = 1; o < 64; o <<= 1) { int tt = __shfl_up(s, o); if (lane >= o) s += tt; }
        if (lane == 63) wtot[w] = s;
        __syncthreads();
        int base = 0;
        for (int k = 0; k < w; ++k) base += wtot[k];
        int excl = base + s - vv;
        if (t < BROWS) {
            cur[t] = bstart + excl;
            offs[rbase + t] = bstart + excl;
            deg[rbase + t] = vv;
        }
    }
    __syncthreads();
    const float fbv = fb[0];
    for (int e = bstart + t; e < bend; e += 256) {
        unsigned pk = part[e];
        int rl = (int)(pk >> 17);
        int c = (int)(pk & 0x1FFFFu);
        float tval = sil[rl] + sj[c] + fbv;
        float sg = 1.f / (1.f + expf(-tval));
        float l2 = log2f(dial[rl] * dia[c]);
        float val = exp2f(-sg * l2);
        int pos = atomicAdd(&cur[rl], 1);
        epack[pos] = make_int2(c, __float_as_int(val));
    }
}

// ------- Kernel 7: per-node gather-accumulate + ReLU, 8-edge deep MLP -------
__global__ __launch_bounds__(256) void kgather(
        const int* __restrict__ offs, const int* __restrict__ deg,
        const int2* __restrict__ epack,
        const unsigned short* __restrict__ psb, float* __restrict__ out) {
    int lane = threadIdx.x & 31;
    int node = blockIdx.x * 8 + (threadIdx.x >> 5);
    if (node >= N_NODES) return;
    int start = offs[node], d = deg[node];
    const int2* ep = epack + start;
    float a0 = 0.f, a1 = 0.f, a2 = 0.f, a3 = 0.f;
    int k = 0;
    for (; k + 8 <= d; k += 8) {
        int2 e0 = ep[k],     e1 = ep[k + 1], e2 = ep[k + 2], e3 = ep[k + 3];
        int2 e4 = ep[k + 4], e5 = ep[k + 5], e6 = ep[k + 6], e7 = ep[k + 7];
        ushort4 p0 = *(const ushort4*)&psb[(size_t)e0.x * OUT_DIM + lane * 4];
        ushort4 p1 = *(const ushort4*)&psb[(size_t)e1.x * OUT_DIM + lane * 4];
        ushort4 p2 = *(const ushort4*)&psb[(size_t)e2.x * OUT_DIM + lane * 4];
        ushort4 p3 = *(const ushort4*)&psb[(size_t)e3.x * OUT_DIM + lane * 4];
        ushort4 p4 = *(const ushort4*)&psb[(size_t)e4.x * OUT_DIM + lane * 4];
        ushort4 p5 = *(const ushort4*)&psb[(size_t)e5.x * OUT_DIM + lane * 4];
        ushort4 p6 = *(const ushort4*)&psb[(size_t)e6.x * OUT_DIM + lane * 4];
        ushort4 p7 = *(const ushort4*)&psb[(size_t)e7.x * OUT_DIM + lane * 4];
        float v0 = __int_as_float(e0.y), v1 = __int_as_float(e1.y);
        float v2 = __int_as_float(e2.y), v3 = __int_as_float(e3.y);
        float v4 = __int_as_float(e4.y), v5 = __int_as_float(e5.y);
        float v6 = __int_as_float(e6.y), v7 = __int_as_float(e7.y);
        a0 = fmaf(v0, bf2f(p0.x), a0); a1 = fmaf(v0, bf2f(p0.y), a1);
        a2 = fmaf(v0, bf2f(p0.z), a2); a3 = fmaf(v0, bf2f(p0.w), a3);
        a0 = fmaf(v1, bf2f(p1.x), a0); a1 = fmaf(v1, bf2f(p1.y), a1);
        a2 = fmaf(v1, bf2f(p1.z), a2); a3 = fmaf(v1, bf2f(p1.w), a3);
        a0 = fmaf(v2, bf2f(p2.x), a0); a1 = fmaf(v2, bf2f(p2.y), a1);
        a2 = fmaf(v2, bf2f(p2.z), a2); a3 = fmaf(v2, bf2f(p2.w), a3);
        a0 = fmaf(v3, bf2f(p3.x), a0); a1 = fmaf(v3, bf2f(p3.y), a1);
        a2 = fmaf(v3, bf2f(p3.z), a2); a3 = fmaf(v3, bf2f(p3.w), a3);
        a0 = fmaf(v4, bf2f(p4.x), a0); a1 = fmaf(v4, bf2f(p4.y), a1);
        a2 = fmaf(v4, bf2f(p4.z), a2); a3 = fmaf(v4, bf2f(p4.w), a3);
        a0 = fmaf(v5, bf2f(p5.x), a0); a1 = fmaf(v5, bf2f(p5.y), a1);
        a2 = fmaf(v5, bf2f(p5.z), a2); a3 = fmaf(v5, bf2f(p5.w), a3);
        a0 = fmaf(v6, bf2f(p6.x), a0); a1 = fmaf(v6, bf2f(p6.y), a1);
        a2 = fmaf(v6, bf2f(p6.z), a2); a3 = fmaf(v6, bf2f(p6.w), a3);
        a0 = fmaf(v7, bf2f(p7.x), a0); a1 = fmaf(v7, bf2f(p7.y), a1);
        a2 = fmaf(v7, bf2f(p7.z), a2); a3 = fmaf(v7, bf2f(p7.w), a3);
    }
    for (; k < d; ++k) {
        int2 e0 = ep[k];
        float v0 = __int_as_float(e0.y);
        ushort4 p0 = *(const ushort4*)&psb[(size_t)e0.x * OUT_DIM + lane * 4];
        a0 = fmaf(v0, bf2f(p0.x), a0);
        a1 = fmaf(v0, bf2f(p0.y), a1);
        a2 = fmaf(v0, bf2f(p0.z), a2);
        a3 = fmaf(v0, bf2f(p0.w), a3);
    }
    float4 o;
    o.x = fmaxf(a0, 0.f); o.y = fmaxf(a1, 0.f);
    o.z = fmaxf(a2, 0.f); o.w = fmaxf(a3, 0.f);
    *(float4*)&out[(size_t)node * OUT_DIM + lane * 4] = o;
}

extern "C" void kernel_launch(void* const* d_in, const int* in_sizes, int n_in,
                              void* d_out, int out_size, void* d_ws, size_t ws_size,
                              hipStream_t stream) {
    const float* x   = (const float*)d_in[0];
    const float* W   = (const float*)d_in[1];
    const float* fsW = (const float*)d_in[2];
    const float* fw  = (const float*)d_in[3];
    const float* fb  = (const float*)d_in[4];
    const float* dia = (const float*)d_in[5];
    const int*   row = (const int*)d_in[6];
    const int*   col = (const int*)d_in[7];
    float* out = (float*)d_out;

    char* p = (char*)d_ws;
    auto alloc = [&](size_t bytes) -> char* {
        char* r = p; p += (bytes + 255) & ~(size_t)255; return r;
    };
    float* u      = (float*)alloc(256 * 4);
    float* v      = (float*)alloc(256 * 4);
    unsigned short* wtb = (unsigned short*)alloc((size_t)128 * 256 * 2);
    float* si     = (float*)alloc((size_t)N_NODES * 4);
    float* sj     = (float*)alloc((size_t)N_NODES * 4);
    int*   deg    = (int*)alloc((size_t)N_NODES * 4);
    int*   offs   = (int*)alloc((size_t)N_NODES * 4);
    unsigned short* psb = (unsigned short*)alloc((size_t)N_NODES * OUT_DIM * 2);
    int*   hist_t = (int*)alloc((size_t)NBK * PBLK * 4);
    int*   bpre   = (int*)alloc((size_t)(NBK + 1) * 4);
    int*   off    = (int*)alloc((size_t)NBK * PBLK * 4);
    unsigned int* part = (unsigned int*)alloc((size_t)N_EDGES * 4);
    int2*  epack  = (int2*)alloc((size_t)N_EDGES * 8);

    kprep<<<PBLK + 1, 256, 0, stream>>>(fsW, fw, W, row, u, v, wtb, hist_t);
    kbscan<<<1, 1024, 0, stream>>>(hist_t, bpre);
    koff<<<NBK, PBLK, 0, stream>>>(hist_t, bpre, off);
    gpart<<<PBLK + (N_NODES + 63) / 64, 256, 0, stream>>>(
        x, wtb, u, v, psb, si, sj, row, col, off, part);
    kpart2<<<NBK, 256, 0, stream>>>(part, bpre, si, sj, dia, fb, epack, offs, deg);
    kgather<<<N_NODES / 8, 256, 0, stream>>>(offs, deg, epack, psb, out);
}

// Round 25
// 167.375 us; speedup vs baseline: 1.0466x; 1.0466x over previous
//
#include <hip/hip_runtime.h>

#define N_NODES 100000
#define N_EDGES 1600000
#define IN_DIM 256
#define OUT_DIM 128
#define BROWS 100    // rows per bucket
#define NBK 1000     // buckets (100000/100)
#define PBLK 128     // partition blocks
#define EPB 12500    // edges per partition block

typedef __attribute__((ext_vector_type(4))) float f32x4;
typedef __attribute__((ext_vector_type(8))) short s16x8;

__device__ inline unsigned short f2bf(float f) {
    union { float f; unsigned int u; } a; a.f = f;
    unsigned int r = a.u + 0x7fffu + ((a.u >> 16) & 1u);
    return (unsigned short)(r >> 16);
}
__device__ inline float bf2f(unsigned short h) {
    union { unsigned int u; float f; } a; a.u = ((unsigned int)h) << 16;
    return a.f;
}
__device__ inline void gload16(const void* g, void* l) {
    __builtin_amdgcn_global_load_lds(
        (const __attribute__((address_space(1))) void*)g,
        (__attribute__((address_space(3))) void*)l, 16, 0, 0);
}

// ---- Kernel 0 (fused): wt transpose + per-(block,bucket) histogram (+bsum) + u/v ----
__global__ __launch_bounds__(256) void kprep(
        const float* __restrict__ fsW, const float* __restrict__ fw,
        const float* __restrict__ W, const int* __restrict__ row,
        float* __restrict__ u, float* __restrict__ v,
        unsigned short* __restrict__ wt, int* __restrict__ hist_t,
        int* __restrict__ bsum) {
    __shared__ int h[NBK];
    __shared__ float wi[128], wj[128];
    const int t = threadIdx.x, blk = blockIdx.x;
    if (blk < PBLK) {
        wt[blk * 256 + t] = f2bf(W[(size_t)t * 128 + blk]);
        for (int b = t; b < NBK; b += 256) h[b] = 0;
        __syncthreads();
        const int e0 = blk * EPB;
        for (int i = t; i < EPB; i += 256)
            atomicAdd(&h[row[e0 + i] / BROWS], 1);
        __syncthreads();
        for (int b = t; b < NBK; b += 256) {
            hist_t[b * PBLK + blk] = h[b];
            atomicAdd(&bsum[b], h[b]);     // fold per-bucket totals for kbscan
        }
    } else {
        if (t < 128) wi[t] = fw[t]; else wj[t - 128] = fw[t];
        __syncthreads();
        const float* rowp = fsW + (size_t)t * OUT_DIM;
        float su = 0.f, sv = 0.f;
        for (int d = 0; d < 128; d += 4) {
            float4 a = *(const float4*)(rowp + d);
            su += a.x * wi[d] + a.y * wi[d + 1] + a.z * wi[d + 2] + a.w * wi[d + 3];
            sv += a.x * wj[d] + a.y * wj[d + 1] + a.z * wj[d + 2] + a.w * wj[d + 3];
        }
        u[t] = su; v[t] = sv;
    }
}

// ------- Kernel 3: exclusive scan of precomputed bucket sums (single block, tiny) -------
__global__ __launch_bounds__(1024) void kbscan(const int* __restrict__ bsum,
                                               int* __restrict__ bpre) {
    __shared__ int s[1024];
    const int t = threadIdx.x;
    int v = (t < NBK) ? bsum[t] : 0;
    s[t] = v;
    __syncthreads();
    for (int off = 1; off < 1024; off <<= 1) {
        int nv = (t >= off) ? s[t - off] : 0;
        __syncthreads();
        s[t] += nv;
        __syncthreads();
    }
    if (t < NBK) bpre[t] = s[t] - v;
    if (t == 1023) bpre[NBK] = s[1023];
}

// ------- Kernel 4: per-(bucket,block) offsets -------
__global__ __launch_bounds__(128) void koff(const int* __restrict__ hist_t,
                                            const int* __restrict__ bpre,
                                            int* __restrict__ off) {
    const int b = blockIdx.x, t = threadIdx.x;
    const int lane = t & 63, w = t >> 6;
    int v = hist_t[b * PBLK + t];
    int s = v;
#pragma unroll
    for (int o = 1; o < 64; o <<= 1) { int tt = __shfl_up(s, o); if (lane >= o) s += tt; }
    __shared__ int ws2[2];
    if (lane == 63) ws2[w] = s;
    __syncthreads();
    int base = (w == 1) ? ws2[0] : 0;
    off[b * PBLK + t] = bpre[b] + base + (s - v);
}

// ------- Kernel G (fused): blocks [0,PBLK) = edge partition; rest = MFMA GEMM -------
// gemm: async f32 staging via global_load_lds (swizzled source, linear LDS dest),
// f32->bf16 via v_cvt_pk in the MFMA phase, si/sj read from LDS post-barrier.
__global__ __launch_bounds__(256) void gpart(
        const float* __restrict__ x, const unsigned short* __restrict__ wt,
        const float* __restrict__ u, const float* __restrict__ v,
        unsigned short* __restrict__ psb, float* __restrict__ si, float* __restrict__ sj,
        const int* __restrict__ row, const int* __restrict__ col,
        const int* __restrict__ off, unsigned int* __restrict__ part) {
    __shared__ char ldsraw[16640];   // 16 KB f32 stage / 16 KB C-tile / kpart1 cursors

    const int t = threadIdx.x;

    if (blockIdx.x < PBLK) {
        // ================= kpart1: partition edges into bucket runs =================
        int* cur = (int*)ldsraw;
        const int blk = blockIdx.x;
        for (int b = t; b < NBK; b += 256) cur[b] = off[b * PBLK + blk];
        __syncthreads();
        const int e0 = blk * EPB;
        for (int i = t; i < EPB; i += 256) {
            int r = row[e0 + i], c = col[e0 + i];
            int b = r / BROWS;
            int rl = r - b * BROWS;
            int pos = atomicAdd(&cur[b], 1);
            part[pos] = ((unsigned)rl << 17) | (unsigned)c;
        }
        return;
    }

    // ================= gemm =================
    const int wave = t >> 6, lane = t & 63;
    const int l15 = lane & 15, lhi = lane >> 4;
    const int rw = t >> 2, quad = t & 3;
    const int brow = (blockIdx.x - PBLK) * 64;
    const int gnode = brow + rw;
    const bool valid = gnode < N_NODES;

    f32x4 acc[4][2];
#pragma unroll
    for (int mi = 0; mi < 4; ++mi)
#pragma unroll
        for (int ni = 0; ni < 2; ++ni) acc[mi][ni] = (f32x4){0.f, 0.f, 0.f, 0.f};
    float su = 0.f, sv = 0.f;

#pragma unroll
    for (int ph = 0; ph < 4; ++ph) {
        // ---- stage 64 rows x 64 f32 (16 KB) async; source pre-swizzled ----
        // involution f(b) = b ^ (((b>>8)&7)<<4); LDS[lo] = global[f(lo)]
#pragma unroll
        for (int i = 0; i < 4; ++i) {
            int lo = i * 4096 + t * 16;
            int q  = lo ^ (((lo >> 8) & 7) << 4);
            int grow = brow + (q >> 8);
            if (grow >= N_NODES) grow = N_NODES - 1;   // clamp: garbage only in guarded rows
            gload16((const char*)x + (size_t)grow * 1024 + ph * 256 + (q & 255),
                    ldsraw + lo);
        }
        __syncthreads();   // drains vmcnt: staged tile visible

        // ---- MFMA: 2 k-steps; A-frags read f32 from LDS, cvt_pk to bf16 ----
        {
            const unsigned short* wb0 = wt + (size_t)(wave * 32 + l15) * IN_DIM + ph * 64 + lhi * 8;
            s16x8 bfr[2][2];
#pragma unroll
            for (int ks = 0; ks < 2; ++ks) {
                bfr[ks][0] = *(const s16x8*)(wb0 + ks * 32);
                bfr[ks][1] = *(const s16x8*)(wb0 + (size_t)16 * IN_DIM + ks * 32);
            }
#pragma unroll
            for (int ks = 0; ks < 2; ++ks) {
                s16x8 afr[4];
#pragma unroll
                for (int mi = 0; mi < 4; ++mi) {
                    const int r = mi * 16 + l15;
                    const int sw = (r & 7) << 4;
                    const int b0 = r * 256 + ks * 128 + lhi * 32;
                    float4 f0 = *(const float4*)(ldsraw + (b0 ^ sw));
                    float4 f1 = *(const float4*)(ldsraw + ((b0 + 16) ^ sw));
                    union { unsigned int w[4]; s16x8 s; } cv;
                    asm("v_cvt_pk_bf16_f32 %0, %1, %2" : "=v"(cv.w[0]) : "v"(f0.x), "v"(f0.y));
                    asm("v_cvt_pk_bf16_f32 %0, %1, %2" : "=v"(cv.w[1]) : "v"(f0.z), "v"(f0.w));
                    asm("v_cvt_pk_bf16_f32 %0, %1, %2" : "=v"(cv.w[2]) : "v"(f1.x), "v"(f1.y));
                    asm("v_cvt_pk_bf16_f32 %0, %1, %2" : "=v"(cv.w[3]) : "v"(f1.z), "v"(f1.w));
                    afr[mi] = cv.s;
                }
#pragma unroll
                for (int mi = 0; mi < 4; ++mi)
#pragma unroll
                    for (int ni = 0; ni < 2; ++ni)
                        acc[mi][ni] = __builtin_amdgcn_mfma_f32_16x16x32_bf16(
                            afr[mi], bfr[ks][ni], acc[mi][ni], 0, 0, 0);
            }
        }

        // ---- si/sj partials from the staged f32 tile ----
        {
            const float* up = u + ph * 64 + quad * 16;
            const float* vp = v + ph * 64 + quad * 16;
            const int rb_ = rw * 256 + quad * 64;
            const int sw = (rw & 7) << 4;
#pragma unroll
            for (int c = 0; c < 4; ++c) {
                float4 a = *(const float4*)(ldsraw + ((rb_ + c * 16) ^ sw));
                float4 uu = ((const float4*)up)[c];
                float4 vv = ((const float4*)vp)[c];
                su = fmaf(a.x, uu.x, su); su = fmaf(a.y, uu.y, su);
                su = fmaf(a.z, uu.z, su); su = fmaf(a.w, uu.w, su);
                sv = fmaf(a.x, vv.x, sv); sv = fmaf(a.y, vv.y, sv);
                sv = fmaf(a.z, vv.z, sv); sv = fmaf(a.w, vv.w, sv);
            }
        }
        __syncthreads();   // all LDS reads done before next phase's staging
    }

    su += __shfl_xor(su, 1); su += __shfl_xor(su, 2);
    sv += __shfl_xor(sv, 1); sv += __shfl_xor(sv, 2);
    if (quad == 0 && valid) { si[gnode] = su; sj[gnode] = sv; }

    // ---- C-write: fragments -> LDS ([64][128] bf16) -> coalesced global ----
    unsigned short* cl = (unsigned short*)ldsraw;
#pragma unroll
    for (int mi = 0; mi < 4; ++mi)
#pragma unroll
        for (int ni = 0; ni < 2; ++ni) {
            const int colb = wave * 32 + ni * 16 + l15;
#pragma unroll
            for (int j = 0; j < 4; ++j)
                cl[(mi * 16 + lhi * 4 + j) * 128 + colb] = f2bf(acc[mi][ni][j]);
        }
    __syncthreads();
    {
        const int rl = t >> 2;
        const int cb = (t & 3) * 32;
        if (brow + rl < N_NODES) {
            const uint4* src = (const uint4*)&cl[rl * 128 + cb];
            uint4* dst = (uint4*)&psb[(size_t)(brow + rl) * OUT_DIM + cb];
            dst[0] = src[0]; dst[1] = src[1]; dst[2] = src[2]; dst[3] = src[3];
        }
    }
}

// ------- Kernel 6: per-bucket row-histogram + local scan -> offs/deg, CSR + value -------
__global__ __launch_bounds__(256) void kpart2(const unsigned int* __restrict__ part,
                                              const int* __restrict__ bpre,
                                              const float* __restrict__ si,
                                              const float* __restrict__ sj,
                                              const float* __restrict__ dia,
                                              const float* __restrict__ fb,
                                              int2* __restrict__ epack,
                                              int* __restrict__ offs,
                                              int* __restrict__ deg) {
    __shared__ int cnt[BROWS];
    __shared__ int cur[BROWS];
    __shared__ float sil[BROWS], dial[BROWS];
    __shared__ int wtot[4];
    const int b = blockIdx.x, t = threadIdx.x;
    const int rbase = b * BROWS;
    if (t < BROWS) {
        cnt[t] = 0;
        sil[t] = si[rbase + t];
        dial[t] = dia[rbase + t];
    }
    __syncthreads();
    const int bstart = bpre[b], bend = bpre[b + 1];
    for (int e = bstart + t; e < bend; e += 256)
        atomicAdd(&cnt[part[e] >> 17], 1);
    __syncthreads();
    {
        int vv = (t < BROWS) ? cnt[t] : 0;
        int lane = t & 63, w = t >> 6;
        int s = vv;
#pragma unroll
        for (int o = 1; o < 64; o <<= 1) { int tt = __shfl_up(s, o); if (lane >= o) s += tt; }
        if (lane == 63) wtot[w] = s;
        __syncthreads();
        int base = 0;
        for (int k = 0; k < w; ++k) base += wtot[k];
        int excl = base + s - vv;
        if (t < BROWS) {
            cur[t] = bstart + excl;
            offs[rbase + t] = bstart + excl;
            deg[rbase + t] = vv;
        }
    }
    __syncthreads();
    const float fbv = fb[0];
    for (int e = bstart + t; e < bend; e += 256) {
        unsigned pk = part[e];
        int rl = (int)(pk >> 17);
        int c = (int)(pk & 0x1FFFFu);
        float tval = sil[rl] + sj[c] + fbv;
        float sg = 1.f / (1.f + expf(-tval));
        float l2 = log2f(dial[rl] * dia[c]);
        float val = exp2f(-sg * l2);
        int pos = atomicAdd(&cur[rl], 1);
        epack[pos] = make_int2(c, __float_as_int(val));
    }
}

// ------- Kernel 7: per-node gather-accumulate + ReLU, 8-edge deep MLP -------
__global__ __launch_bounds__(256) void kgather(
        const int* __restrict__ offs, const int* __restrict__ deg,
        const int2* __restrict__ epack,
        const unsigned short* __restrict__ psb, float* __restrict__ out) {
    int lane = threadIdx.x & 31;
    int node = blockIdx.x * 8 + (threadIdx.x >> 5);
    if (node >= N_NODES) return;
    int start = offs[node], d = deg[node];
    const int2* ep = epack + start;
    float a0 = 0.f, a1 = 0.f, a2 = 0.f, a3 = 0.f;
    int k = 0;
    for (; k + 8 <= d; k += 8) {
        int2 e0 = ep[k],     e1 = ep[k + 1], e2 = ep[k + 2], e3 = ep[k + 3];
        int2 e4 = ep[k + 4], e5 = ep[k + 5], e6 = ep[k + 6], e7 = ep[k + 7];
        ushort4 p0 = *(const ushort4*)&psb[(size_t)e0.x * OUT_DIM + lane * 4];
        ushort4 p1 = *(const ushort4*)&psb[(size_t)e1.x * OUT_DIM + lane * 4];
        ushort4 p2 = *(const ushort4*)&psb[(size_t)e2.x * OUT_DIM + lane * 4];
        ushort4 p3 = *(const ushort4*)&psb[(size_t)e3.x * OUT_DIM + lane * 4];
        ushort4 p4 = *(const ushort4*)&psb[(size_t)e4.x * OUT_DIM + lane * 4];
        ushort4 p5 = *(const ushort4*)&psb[(size_t)e5.x * OUT_DIM + lane * 4];
        ushort4 p6 = *(const ushort4*)&psb[(size_t)e6.x * OUT_DIM + lane * 4];
        ushort4 p7 = *(const ushort4*)&psb[(size_t)e7.x * OUT_DIM + lane * 4];
        float v0 = __int_as_float(e0.y), v1 = __int_as_float(e1.y);
        float v2 = __int_as_float(e2.y), v3 = __int_as_float(e3.y);
        float v4 = __int_as_float(e4.y), v5 = __int_as_float(e5.y);
        float v6 = __int_as_float(e6.y), v7 = __int_as_float(e7.y);
        a0 = fmaf(v0, bf2f(p0.x), a0); a1 = fmaf(v0, bf2f(p0.y), a1);
        a2 = fmaf(v0, bf2f(p0.z), a2); a3 = fmaf(v0, bf2f(p0.w), a3);
        a0 = fmaf(v1, bf2f(p1.x), a0); a1 = fmaf(v1, bf2f(p1.y), a1);
        a2 = fmaf(v1, bf2f(p1.z), a2); a3 = fmaf(v1, bf2f(p1.w), a3);
        a0 = fmaf(v2, bf2f(p2.x), a0); a1 = fmaf(v2, bf2f(p2.y), a1);
        a2 = fmaf(v2, bf2f(p2.z), a2); a3 = fmaf(v2, bf2f(p2.w), a3);
        a0 = fmaf(v3, bf2f(p3.x), a0); a1 = fmaf(v3, bf2f(p3.y), a1);
        a2 = fmaf(v3, bf2f(p3.z), a2); a3 = fmaf(v3, bf2f(p3.w), a3);
        a0 = fmaf(v4, bf2f(p4.x), a0); a1 = fmaf(v4, bf2f(p4.y), a1);
        a2 = fmaf(v4, bf2f(p4.z), a2); a3 = fmaf(v4, bf2f(p4.w), a3);
        a0 = fmaf(v5, bf2f(p5.x), a0); a1 = fmaf(v5, bf2f(p5.y), a1);
        a2 = fmaf(v5, bf2f(p5.z), a2); a3 = fmaf(v5, bf2f(p5.w), a3);
        a0 = fmaf(v6, bf2f(p6.x), a0); a1 = fmaf(v6, bf2f(p6.y), a1);
        a2 = fmaf(v6, bf2f(p6.z), a2); a3 = fmaf(v6, bf2f(p6.w), a3);
        a0 = fmaf(v7, bf2f(p7.x), a0); a1 = fmaf(v7, bf2f(p7.y), a1);
        a2 = fmaf(v7, bf2f(p7.z), a2); a3 = fmaf(v7, bf2f(p7.w), a3);
    }
    for (; k < d; ++k) {
        int2 e0 = ep[k];
        float v0 = __int_as_float(e0.y);
        ushort4 p0 = *(const ushort4*)&psb[(size_t)e0.x * OUT_DIM + lane * 4];
        a0 = fmaf(v0, bf2f(p0.x), a0);
        a1 = fmaf(v0, bf2f(p0.y), a1);
        a2 = fmaf(v0, bf2f(p0.z), a2);
        a3 = fmaf(v0, bf2f(p0.w), a3);
    }
    float4 o;
    o.x = fmaxf(a0, 0.f); o.y = fmaxf(a1, 0.f);
    o.z = fmaxf(a2, 0.f); o.w = fmaxf(a3, 0.f);
    *(float4*)&out[(size_t)node * OUT_DIM + lane * 4] = o;
}

extern "C" void kernel_launch(void* const* d_in, const int* in_sizes, int n_in,
                              void* d_out, int out_size, void* d_ws, size_t ws_size,
                              hipStream_t stream) {
    const float* x   = (const float*)d_in[0];
    const float* W   = (const float*)d_in[1];
    const float* fsW = (const float*)d_in[2];
    const float* fw  = (const float*)d_in[3];
    const float* fb  = (const float*)d_in[4];
    const float* dia = (const float*)d_in[5];
    const int*   row = (const int*)d_in[6];
    const int*   col = (const int*)d_in[7];
    float* out = (float*)d_out;

    char* p = (char*)d_ws;
    auto alloc = [&](size_t bytes) -> char* {
        char* r = p; p += (bytes + 255) & ~(size_t)255; return r;
    };
    float* u      = (float*)alloc(256 * 4);
    float* v      = (float*)alloc(256 * 4);
    unsigned short* wtb = (unsigned short*)alloc((size_t)128 * 256 * 2);
    float* si     = (float*)alloc((size_t)N_NODES * 4);
    float* sj     = (float*)alloc((size_t)N_NODES * 4);
    int*   deg    = (int*)alloc((size_t)N_NODES * 4);
    int*   offs   = (int*)alloc((size_t)N_NODES * 4);
    unsigned short* psb = (unsigned short*)alloc((size_t)N_NODES * OUT_DIM * 2);
    int*   hist_t = (int*)alloc((size_t)NBK * PBLK * 4);
    int*   bsum   = (int*)alloc((size_t)NBK * 4);
    int*   bpre   = (int*)alloc((size_t)(NBK + 1) * 4);
    int*   off    = (int*)alloc((size_t)NBK * PBLK * 4);
    unsigned int* part = (unsigned int*)alloc((size_t)N_EDGES * 4);
    int2*  epack  = (int2*)alloc((size_t)N_EDGES * 8);

    (void)hipMemsetAsync(bsum, 0, (size_t)NBK * 4, stream);

    kprep<<<PBLK + 1, 256, 0, stream>>>(fsW, fw, W, row, u, v, wtb, hist_t, bsum);
    kbscan<<<1, 1024, 0, stream>>>(bsum, bpre);
    koff<<<NBK, PBLK, 0, stream>>>(hist_t, bpre, off);
    gpart<<<PBLK + (N_NODES + 63) / 64, 256, 0, stream>>>(
        x, wtb, u, v, psb, si, sj, row, col, off, part);
    kpart2<<<NBK, 256, 0, stream>>>(part, bpre, si, sj, dia, fb, epack, offs, deg);
    kgather<<<N_NODES / 8, 256, 0, stream>>>(offs, deg, epack, psb, out);
}